// Round 4
// baseline (416.376 us; speedup 1.0000x reference)
//
#include <hip/hip_runtime.h>
#include <math.h>

// Problem constants (fixed by setup_inputs)
#define BATCH 8192
#define EDIM  4096
#define NBINS 64     // 8x8 pair-histogram bins
#define NREP  64     // replicated global histograms to spread atomic contention

// Workspace layout (bytes). Requires ws_size >= 163840 (160 KB).
//   [0,      16384)  : hist      NREP*NBINS uint32
//   [16384,  49152)  : row_ent   8192 f32   (-sum psi*log(psi+1e-10) per row)
//   [49152,  81920)  : row_std   8192 f32   (ddof=1 std per row)
//   [81920, 114688)  : row_fsq   8192 f32   (sum field^2 per row)
//   [114688,131072)  : colsum    4096 f32
//   [131072,147456)  : colsumsq  4096 f32
//   [147456,163840)  : pairprod  4096 f32   (sum_b f[b,c]*f[b,c+1])

__global__ __launch_bounds__(256) void psi_pass(const float* __restrict__ psi,
                                                unsigned* __restrict__ ghist,
                                                float* __restrict__ row_ent,
                                                float* __restrict__ row_std) {
  const int r = blockIdx.x;
  const int t = threadIdx.x;
  const float4* row = (const float4*)(psi + (size_t)r * EDIM);

  __shared__ unsigned lhist[NBINS];
  __shared__ float firsts[EDIM / 4];   // first element of each float4 (for cross-thread pairs)
  __shared__ float red[12];

  if (t < NBINS) lhist[t] = 0u;

  float4 v[4];
#pragma unroll
  for (int k = 0; k < 4; ++k) v[k] = row[t + k * 256];
#pragma unroll
  for (int k = 0; k < 4; ++k) firsts[t + k * 256] = v[k].x;
  __syncthreads();   // covers lhist zero-init + firsts visibility

  float s = 0.f, sq = 0.f, pl = 0.f;
#pragma unroll
  for (int k = 0; k < 4; ++k) {
    const int vi = t + k * 256;
    float ee[4] = {v[k].x, v[k].y, v[k].z, v[k].w};
    int q[4];
#pragma unroll
    for (int j = 0; j < 4; ++j) {
      float x = ee[j];
      s += x;
      sq += x * x;
      pl += x * __logf(x + 1e-10f);          // accuracy non-critical: d_eeg clamps at 10
      int qq = (int)floorf(x * 8.0f);
      q[j] = min(max(qq, 0), 7);
    }
#pragma unroll
    for (int j = 0; j < 3; ++j)
      atomicAdd(&lhist[q[j] * 8 + q[j + 1]], 1u);
    if (vi < EDIM / 4 - 1) {
      float xn = firsts[vi + 1];
      int qn = min(max((int)floorf(xn * 8.0f), 0), 7);
      atomicAdd(&lhist[q[3] * 8 + qn], 1u);
    }
  }

  // block reduce s, sq, pl (wave shuffle then LDS across 4 waves)
  for (int off = 32; off; off >>= 1) {
    s  += __shfl_down(s, off);
    sq += __shfl_down(sq, off);
    pl += __shfl_down(pl, off);
  }
  const int w = t >> 6, lane = t & 63;
  if (lane == 0) { red[w] = s; red[4 + w] = sq; red[8 + w] = pl; }
  __syncthreads();   // also guarantees all lhist atomics have landed
  if (t == 0) {
    float S  = red[0] + red[1] + red[2] + red[3];
    float SQ = red[4] + red[5] + red[6] + red[7];
    float PL = red[8] + red[9] + red[10] + red[11];
    row_ent[r] = -PL;
    float var = (SQ - S * S / (float)EDIM) / (float)(EDIM - 1);
    row_std[r] = sqrtf(fmaxf(var, 0.f));
  }
  if (t < NBINS) atomicAdd(&ghist[(blockIdx.x & (NREP - 1)) * NBINS + t], lhist[t]);
}

// One wave per (256-column x 16-row) tile; lane owns 4 consecutive columns via
// one float4 load per row (16 B/lane coalescing sweet spot). 3 of 4 pair
// products are register-internal; the 4th uses a single __shfl_down. Per-row
// sumsq via 6-step wave shuffle reduce + one atomicAdd per row per wave
// (16 column-chunk contenders per row address).
__global__ __launch_bounds__(256) void field_pass(const float* __restrict__ f,
                                                  float* __restrict__ colsum,
                                                  float* __restrict__ colsumsq,
                                                  float* __restrict__ pairprod,
                                                  float* __restrict__ row_fsq) {
  const int gw = (blockIdx.x * 256 + threadIdx.x) >> 6;  // global wave id, 0..8191
  const int lane = threadIdx.x & 63;
  const int cchunk = gw & 15;      // 16 column chunks of 256 columns
  const int rgroup = gw >> 4;      // 512 row groups of 16 rows
  const int c0 = cchunk * 256 + lane * 4;   // first of this lane's 4 columns
  const int r0 = rgroup * (BATCH / 512);
  const bool lastCol = (c0 + 3 == EDIM - 1);  // only cchunk==15, lane==63

  float cs0 = 0.f, cs1 = 0.f, cs2 = 0.f, cs3 = 0.f;
  float cq0 = 0.f, cq1 = 0.f, cq2 = 0.f, cq3 = 0.f;
  float pp0 = 0.f, pp1 = 0.f, pp2 = 0.f, pp3 = 0.f;
#pragma unroll 4
  for (int i = 0; i < BATCH / 512; ++i) {
    const int r = r0 + i;
    const float* rowp = f + (size_t)r * EDIM;
    const float4 v = *(const float4*)(rowp + c0);
    cs0 += v.x; cs1 += v.y; cs2 += v.z; cs3 += v.w;
    cq0 += v.x * v.x; cq1 += v.y * v.y; cq2 += v.z * v.z; cq3 += v.w * v.w;
    pp0 += v.x * v.y; pp1 += v.y * v.z; pp2 += v.z * v.w;
    float nx = __shfl_down(v.x, 1);              // next lane's first column
    if (lane == 63 && !lastCol) nx = rowp[c0 + 4];  // cross-chunk neighbor (L2 hit)
    if (!lastCol) pp3 += v.w * nx;
    float rs = v.x * v.x + v.y * v.y + v.z * v.z + v.w * v.w;
    for (int off = 32; off; off >>= 1) rs += __shfl_down(rs, off);
    if (lane == 0) atomicAdd(&row_fsq[r], rs);
  }
  atomicAdd(&colsum[c0 + 0], cs0);  atomicAdd(&colsumsq[c0 + 0], cq0);
  atomicAdd(&colsum[c0 + 1], cs1);  atomicAdd(&colsumsq[c0 + 1], cq1);
  atomicAdd(&colsum[c0 + 2], cs2);  atomicAdd(&colsumsq[c0 + 2], cq2);
  atomicAdd(&colsum[c0 + 3], cs3);  atomicAdd(&colsumsq[c0 + 3], cq3);
  atomicAdd(&pairprod[c0 + 0], pp0);
  atomicAdd(&pairprod[c0 + 1], pp1);
  atomicAdd(&pairprod[c0 + 2], pp2);
  if (!lastCol) atomicAdd(&pairprod[c0 + 3], pp3);  // pairprod[EDIM-1] unused
}

__device__ double blk_reduce(double v, double* sbuf) {
  const int t = threadIdx.x;
  for (int off = 32; off; off >>= 1) v += __shfl_down(v, off);
  __syncthreads();                 // protect sbuf against reuse from prior call
  if ((t & 63) == 0) sbuf[t >> 6] = v;
  __syncthreads();
  return sbuf[0] + sbuf[1] + sbuf[2] + sbuf[3];
}

__global__ __launch_bounds__(256) void finalize(const unsigned* __restrict__ ghist,
                                                const float* __restrict__ row_ent,
                                                const float* __restrict__ row_std,
                                                const float* __restrict__ row_fsq,
                                                const float* __restrict__ colsum,
                                                const float* __restrict__ colsumsq,
                                                const float* __restrict__ pairprod,
                                                const float* __restrict__ wts,
                                                float* __restrict__ out) {
  const int t = threadIdx.x;
  __shared__ double sbuf[4];

  double se = 0, ss = 0, sm = 0;
  for (int i = t; i < BATCH; i += 256) {
    se += (double)row_ent[i];
    ss += (double)row_std[i];
    sm += (double)sqrtf(row_fsq[i]);
  }
  double SE = blk_reduce(se, sbuf);
  double SS = blk_reduce(ss, sbuf);
  double SM = blk_reduce(sm, sbuf);

  // adjacent-column Pearson corr from uncentered sums (double for the
  // cancellation-heavy cov term; this is the only unclamped, sensitive stat)
  double csum = 0, ccnt = 0;
  for (int e = t; e < EDIM - 1; e += 256) {
    double sa = colsum[e], sb = colsum[e + 1];
    double va = (double)colsumsq[e]     - sa * sa / (double)BATCH;
    double vb = (double)colsumsq[e + 1] - sb * sb / (double)BATCH;
    double cov = (double)pairprod[e] - sa * sb / (double)BATCH;
    double corr = cov / sqrt(va * vb);
    if (!isnan(corr)) { csum += corr; ccnt += 1.0; }
  }
  double CS = blk_reduce(csum, sbuf);
  double CN = blk_reduce(ccnt, sbuf);

  double gs = 0, gq = 0;
  for (int e = t; e < EDIM; e += 256) { gs += (double)colsum[e]; gq += (double)colsumsq[e]; }
  double GS = blk_reduce(gs, sbuf);
  double GQ = blk_reduce(gq, sbuf);

  double hent = 0;
  if (t < NBINS) {
    unsigned long long cnt = 0;
    for (int rrep = 0; rrep < NREP; ++rrep) cnt += (unsigned long long)ghist[rrep * NBINS + t];
    const double total = (double)BATCH * (double)(EDIM - 1);
    double p = (double)cnt / total;
    if (p > 0.0) hent = -p * log2(p);
  }
  double HE = blk_reduce(hent, sbuf);

  if (t == 0) {
    double entropy = SE / (double)BATCH;
    double spat = SS / (double)BATCH;
    double d_eeg = fmin(entropy * spat * 3.0, 10.0);

    double mag = SM / (double)BATCH;
    double mean_corr = (CN > 0.0) ? (CS / CN) : 0.0;
    double h_fmri = fmin(mag * fabs(mean_corr) * 2.0, 5.0);

    double Nf = (double)BATCH * (double)EDIM;
    double gvar = (GQ - GS * GS / Nf) / (Nf - 1.0);
    double fstd = sqrt(fmax(gvar, 0.0));
    double clz = fmin(HE + 0.3 * fstd, 3.0);

    double fci = (double)wts[0] * (d_eeg / 10.0)
               + (double)wts[1] * (h_fmri / 5.0)
               + (double)wts[2] * (clz / 3.0);
    fci = fmin(fmax(fci, 0.0), 1.0);
    out[0] = (float)fci;
  }
}

extern "C" void kernel_launch(void* const* d_in, const int* in_sizes, int n_in,
                              void* d_out, int out_size, void* d_ws, size_t ws_size,
                              hipStream_t stream) {
  const float* psi = (const float*)d_in[0];
  const float* fld = (const float*)d_in[1];
  const float* wts = (const float*)d_in[2];
  float* out = (float*)d_out;

  char* ws = (char*)d_ws;
  unsigned* ghist = (unsigned*)(ws);
  float* row_ent  = (float*)(ws + 16384);
  float* row_std  = (float*)(ws + 49152);
  float* row_fsq  = (float*)(ws + 81920);
  float* colsum   = (float*)(ws + 114688);
  float* colsumsq = (float*)(ws + 131072);
  float* pairprod = (float*)(ws + 147456);

  // ws is re-poisoned to 0xAA before every timed launch; zero the atomic targets.
  hipMemsetAsync(d_ws, 0, 163840, stream);

  psi_pass<<<BATCH, 256, 0, stream>>>(psi, ghist, row_ent, row_std);
  field_pass<<<2048, 256, 0, stream>>>(fld, colsum, colsumsq, pairprod, row_fsq);
  finalize<<<1, 256, 0, stream>>>(ghist, row_ent, row_std, row_fsq,
                                  colsum, colsumsq, pairprod, wts, out);
}

// Round 6
// 351.819 us; speedup vs baseline: 1.1835x; 1.1835x over previous
//
#include <hip/hip_runtime.h>
#include <math.h>

// Problem constants (fixed by setup_inputs)
#define BATCH 8192
#define EDIM  4096
#define NBINS 64        // 8x8 pair-histogram bins
#define NGRP  128       // field row-groups, primary path (2048 waves total)
#define ROWSW (BATCH / NGRP)   // 64 rows per wave
#define NCHK  16        // column chunks of 256
#define NREP_FB 64      // fallback: replicated global histograms

// ---------------- PRIMARY workspace layout (floats/u32). ws >= 9,062,400 B --
#define OFF_HISTP   0u                           // 8192*64 u32 per-block hist
#define OFF_CSP     (2u * 1024 * 1024 / 4)       // 128*4096 f32 colsum partials
#define OFF_CQP     (4u * 1024 * 1024 / 4)
#define OFF_PPP     (6u * 1024 * 1024 / 4)
#define OFF_RFSQP   (8u * 1024 * 1024 / 4)       // 16*8192 f32 row-sumsq partials
#define OFF_ROWENT  (OFF_RFSQP + NCHK * BATCH)
#define OFF_ROWSTD  (OFF_ROWENT + BATCH)
#define OFF_ROWFSQ  (OFF_ROWSTD + BATCH)
#define OFF_COLSUM  (OFF_ROWFSQ + BATCH)
#define OFF_COLSQ   (OFF_COLSUM + EDIM)
#define OFF_PAIRP   (OFF_COLSQ + EDIM)
#define OFF_HIST2   (OFF_PAIRP + EDIM)           // 8*64 u32
#define PRIMARY_WS_BYTES ((OFF_HIST2 + 2 * NBINS) * 4)   // ~9.06 MB

// ---------------- FALLBACK workspace layout (bytes). ws >= 163,840 B --------
//  [0,16384) ghist NREP_FB*64 u32 | [16384) row_ent | [49152) row_std
//  [81920) row_fsq | [114688) colsum | [131072) colsumsq | [147456) pairprod

// psi: one block per row. fb=0 -> plain per-block hist store (primary);
// fb=1 -> atomicAdd into 64 replicated global histograms (fallback).
__global__ __launch_bounds__(256) void psi_pass(const float* __restrict__ psi,
                                                unsigned* __restrict__ hist,
                                                float* __restrict__ row_ent,
                                                float* __restrict__ row_std,
                                                int fb) {
  const int r = blockIdx.x;
  const int t = threadIdx.x;
  const float4* row = (const float4*)(psi + (size_t)r * EDIM);

  __shared__ unsigned lhist[NBINS];
  __shared__ float firsts[EDIM / 4];   // first element of each float4 (cross-thread pairs)
  __shared__ float red[12];

  if (t < NBINS) lhist[t] = 0u;

  float4 v[4];
#pragma unroll
  for (int k = 0; k < 4; ++k) v[k] = row[t + k * 256];
#pragma unroll
  for (int k = 0; k < 4; ++k) firsts[t + k * 256] = v[k].x;
  __syncthreads();   // covers lhist zero-init + firsts visibility

  float s = 0.f, sq = 0.f, pl = 0.f;
#pragma unroll
  for (int k = 0; k < 4; ++k) {
    const int vi = t + k * 256;
    float ee[4] = {v[k].x, v[k].y, v[k].z, v[k].w};
    int q[4];
#pragma unroll
    for (int j = 0; j < 4; ++j) {
      float x = ee[j];
      s += x;
      sq += x * x;
      pl += x * __logf(x + 1e-10f);      // accuracy non-critical: d_eeg clamps at 10
      int qq = (int)floorf(x * 8.0f);
      q[j] = min(max(qq, 0), 7);
    }
#pragma unroll
    for (int j = 0; j < 3; ++j)
      atomicAdd(&lhist[q[j] * 8 + q[j + 1]], 1u);   // LDS-scope atomic: cheap
    if (vi < EDIM / 4 - 1) {
      float xn = firsts[vi + 1];
      int qn = min(max((int)floorf(xn * 8.0f), 0), 7);
      atomicAdd(&lhist[q[3] * 8 + qn], 1u);
    }
  }

  // block reduce s, sq, pl
  for (int off = 32; off; off >>= 1) {
    s  += __shfl_down(s, off);
    sq += __shfl_down(sq, off);
    pl += __shfl_down(pl, off);
  }
  const int w = t >> 6, lane = t & 63;
  if (lane == 0) { red[w] = s; red[4 + w] = sq; red[8 + w] = pl; }
  __syncthreads();   // also guarantees all lhist atomics have landed
  if (t == 0) {
    float S  = red[0] + red[1] + red[2] + red[3];
    float SQ = red[4] + red[5] + red[6] + red[7];
    float PL = red[8] + red[9] + red[10] + red[11];
    row_ent[r] = -PL;
    float var = (SQ - S * S / (float)EDIM) / (float)(EDIM - 1);
    row_std[r] = sqrtf(fmaxf(var, 0.f));
  }
  if (t < NBINS) {
    if (fb) atomicAdd(&hist[(size_t)(r & (NREP_FB - 1)) * NBINS + t], lhist[t]);
    else    hist[(size_t)r * NBINS + t] = lhist[t];
  }
}

// PRIMARY field: 2048 waves; wave owns a 256-col x 64-row tile; lane owns 4
// consecutive columns. NO conditional loads, NO atomics -> 8 loads in flight.
// Chunk-boundary pair products are computed in reduce_pass.
__global__ __launch_bounds__(256) void field_pass(const float* __restrict__ f,
                                                  float* __restrict__ cs_part,
                                                  float* __restrict__ cq_part,
                                                  float* __restrict__ pp_part,
                                                  float* __restrict__ rfsq_part) {
  const int gw = (blockIdx.x * 256 + threadIdx.x) >> 6;  // 0..2047
  const int lane = threadIdx.x & 63;
  const int cchunk = gw & (NCHK - 1);
  const int g = gw >> 4;                 // row group 0..127
  const int c0 = cchunk * 256 + lane * 4;
  const int r0 = g * ROWSW;

  float cs0 = 0.f, cs1 = 0.f, cs2 = 0.f, cs3 = 0.f;
  float cq0 = 0.f, cq1 = 0.f, cq2 = 0.f, cq3 = 0.f;
  float pp0 = 0.f, pp1 = 0.f, pp2 = 0.f, pp3 = 0.f;
#pragma unroll 8
  for (int i = 0; i < ROWSW; ++i) {
    const int r = r0 + i;
    const float4 v = *(const float4*)(f + (size_t)r * EDIM + c0);
    cs0 += v.x; cs1 += v.y; cs2 += v.z; cs3 += v.w;
    cq0 = fmaf(v.x, v.x, cq0); cq1 = fmaf(v.y, v.y, cq1);
    cq2 = fmaf(v.z, v.z, cq2); cq3 = fmaf(v.w, v.w, cq3);
    pp0 = fmaf(v.x, v.y, pp0); pp1 = fmaf(v.y, v.z, pp1); pp2 = fmaf(v.z, v.w, pp2);
    float nx = __shfl_down(v.x, 1);            // next lane's first column
    if (lane != 63) pp3 = fmaf(v.w, nx, pp3);  // boundary pair handled elsewhere
    float rs = fmaf(v.x, v.x, fmaf(v.y, v.y, fmaf(v.z, v.z, v.w * v.w)));
    for (int off = 32; off; off >>= 1) rs += __shfl_down(rs, off);
    if (lane == 0) rfsq_part[(size_t)cchunk * BATCH + r] = rs;  // plain store
  }
  const size_t cb = (size_t)g * EDIM + c0;
  *(float4*)(cs_part + cb) = make_float4(cs0, cs1, cs2, cs3);
  *(float4*)(cq_part + cb) = make_float4(cq0, cq1, cq2, cq3);
  *(float4*)(pp_part + cb) = make_float4(pp0, pp1, pp2, pp3);  // lane63 slot = 0
}

// FALLBACK field: 8192 waves, 16 rows each, global-atomic accumulation.
// Differs from the R4-measured version ONLY by removing the in-loop
// conditional load (the vmcnt-drain); boundary pairs -> boundary_pass.
__global__ __launch_bounds__(256) void field_pass_fb(const float* __restrict__ f,
                                                     float* __restrict__ colsum,
                                                     float* __restrict__ colsumsq,
                                                     float* __restrict__ pairprod,
                                                     float* __restrict__ row_fsq) {
  const int gw = (blockIdx.x * 256 + threadIdx.x) >> 6;  // 0..8191
  const int lane = threadIdx.x & 63;
  const int cchunk = gw & 15;
  const int rgroup = gw >> 4;      // 512 row groups of 16 rows
  const int c0 = cchunk * 256 + lane * 4;
  const int r0 = rgroup * (BATCH / 512);

  float cs0 = 0.f, cs1 = 0.f, cs2 = 0.f, cs3 = 0.f;
  float cq0 = 0.f, cq1 = 0.f, cq2 = 0.f, cq3 = 0.f;
  float pp0 = 0.f, pp1 = 0.f, pp2 = 0.f, pp3 = 0.f;
#pragma unroll 8
  for (int i = 0; i < BATCH / 512; ++i) {
    const int r = r0 + i;
    const float4 v = *(const float4*)(f + (size_t)r * EDIM + c0);
    cs0 += v.x; cs1 += v.y; cs2 += v.z; cs3 += v.w;
    cq0 = fmaf(v.x, v.x, cq0); cq1 = fmaf(v.y, v.y, cq1);
    cq2 = fmaf(v.z, v.z, cq2); cq3 = fmaf(v.w, v.w, cq3);
    pp0 = fmaf(v.x, v.y, pp0); pp1 = fmaf(v.y, v.z, pp1); pp2 = fmaf(v.z, v.w, pp2);
    float nx = __shfl_down(v.x, 1);
    if (lane != 63) pp3 = fmaf(v.w, nx, pp3);
    float rs = fmaf(v.x, v.x, fmaf(v.y, v.y, fmaf(v.z, v.z, v.w * v.w)));
    for (int off = 32; off; off >>= 1) rs += __shfl_down(rs, off);
    if (lane == 0) atomicAdd(&row_fsq[r], rs);
  }
  atomicAdd(&colsum[c0 + 0], cs0);  atomicAdd(&colsumsq[c0 + 0], cq0);
  atomicAdd(&colsum[c0 + 1], cs1);  atomicAdd(&colsumsq[c0 + 1], cq1);
  atomicAdd(&colsum[c0 + 2], cs2);  atomicAdd(&colsumsq[c0 + 2], cq2);
  atomicAdd(&colsum[c0 + 3], cs3);  atomicAdd(&colsumsq[c0 + 3], cq3);
  atomicAdd(&pairprod[c0 + 0], pp0);
  atomicAdd(&pairprod[c0 + 1], pp1);
  atomicAdd(&pairprod[c0 + 2], pp2);
  if (lane != 63) atomicAdd(&pairprod[c0 + 3], pp3);  // boundary slots via boundary_pass
}

// Boundary pair columns c = 255, 511, ..., 3839 (15 blocks). Plain store;
// runs after field completes (stream order). Input is L3-hot.
__global__ __launch_bounds__(256) void boundary_pass(const float* __restrict__ f,
                                                     float* __restrict__ pairprod) {
  __shared__ float sred[4];
  const int c = blockIdx.x * 256 + 255;
  const int t = threadIdx.x;
  float acc = 0.f;
  for (int r = t; r < BATCH; r += 256)
    acc = fmaf(f[(size_t)r * EDIM + c], f[(size_t)r * EDIM + c + 1], acc);
  for (int off = 32; off; off >>= 1) acc += __shfl_down(acc, off);
  if ((t & 63) == 0) sred[t >> 6] = acc;
  __syncthreads();
  if (t == 0) pairprod[c] = sred[0] + sred[1] + sred[2] + sred[3];
}

// PRIMARY reduce: folds partials. Blocks 0..15 colsum, 16..31 colsumsq,
// 32..47 pairprod (non-boundary), 48..79 row_fsq, 80..87 histogram, 88..102
// boundary pair columns.
__global__ __launch_bounds__(256) void reduce_pass(const float* __restrict__ f,
                                                   const unsigned* __restrict__ hist_part,
                                                   const float* __restrict__ cs_part,
                                                   const float* __restrict__ cq_part,
                                                   const float* __restrict__ pp_part,
                                                   const float* __restrict__ rfsq_part,
                                                   float* __restrict__ colsum,
                                                   float* __restrict__ colsumsq,
                                                   float* __restrict__ pairprod,
                                                   float* __restrict__ row_fsq,
                                                   unsigned* __restrict__ hist2) {
  const int b = blockIdx.x;
  const int t = threadIdx.x;

  if (b < 48) {                       // column-stat folds
    const int stat = b >> 4;          // 0 cs, 1 cq, 2 pp
    const int c = (b & 15) * 256 + t;
    const float* part = (stat == 0) ? cs_part : (stat == 1) ? cq_part : pp_part;
    float acc = 0.f;
#pragma unroll 8
    for (int g = 0; g < NGRP; ++g) acc += part[(size_t)g * EDIM + c];
    if (stat == 0) colsum[c] = acc;
    else if (stat == 1) colsumsq[c] = acc;
    else if ((c & 255) != 255) pairprod[c] = acc;  // boundary cols from blocks 88+
  } else if (b < 80) {                // row_fsq fold
    const int r = (b - 48) * 256 + t;
    float acc = 0.f;
#pragma unroll
    for (int k = 0; k < NCHK; ++k) acc += rfsq_part[(size_t)k * BATCH + r];
    row_fsq[r] = acc;
  } else if (b < 88) {                // histogram: 1024 psi-blocks -> 1 replica
    __shared__ unsigned hred[4][NBINS];
    const int j = b - 80;
    const int bin = t & 63, quad = t >> 6;
    unsigned acc = 0u;
    for (int pb = j * 1024 + quad; pb < (j + 1) * 1024; pb += 4)
      acc += hist_part[(size_t)pb * NBINS + bin];
    hred[quad][bin] = acc;
    __syncthreads();
    if (t < NBINS)
      hist2[(size_t)j * NBINS + t] = hred[0][t] + hred[1][t] + hred[2][t] + hred[3][t];
  } else {                            // boundary pair columns
    __shared__ float sred[4];
    const int c = (b - 88) * 256 + 255;
    float acc = 0.f;
    for (int r = t; r < BATCH; r += 256)
      acc = fmaf(f[(size_t)r * EDIM + c], f[(size_t)r * EDIM + c + 1], acc);
    for (int off = 32; off; off >>= 1) acc += __shfl_down(acc, off);
    if ((t & 63) == 0) sred[t >> 6] = acc;
    __syncthreads();
    if (t == 0) pairprod[c] = sred[0] + sred[1] + sred[2] + sred[3];
  }
}

__device__ double blk_reduce(double v, double* sbuf) {
  const int t = threadIdx.x;
  for (int off = 32; off; off >>= 1) v += __shfl_down(v, off);
  __syncthreads();                 // protect sbuf against reuse from prior call
  if ((t & 63) == 0) sbuf[t >> 6] = v;
  __syncthreads();
  return sbuf[0] + sbuf[1] + sbuf[2] + sbuf[3];
}

// Shared finalize; hist has `nreps` replicas of 64 bins (primary 8, fb 64).
__global__ __launch_bounds__(256) void finalize(const unsigned* __restrict__ hist,
                                                int nreps,
                                                const float* __restrict__ row_ent,
                                                const float* __restrict__ row_std,
                                                const float* __restrict__ row_fsq,
                                                const float* __restrict__ colsum,
                                                const float* __restrict__ colsumsq,
                                                const float* __restrict__ pairprod,
                                                const float* __restrict__ wts,
                                                float* __restrict__ out) {
  const int t = threadIdx.x;
  __shared__ double sbuf[4];

  double se = 0, ss = 0, sm = 0;
  for (int i = t; i < BATCH; i += 256) {
    se += (double)row_ent[i];
    ss += (double)row_std[i];
    sm += (double)sqrtf(row_fsq[i]);
  }
  double SE = blk_reduce(se, sbuf);
  double SS = blk_reduce(ss, sbuf);
  double SM = blk_reduce(sm, sbuf);

  // adjacent-column Pearson corr from uncentered sums (double for the
  // cancellation-heavy cov term; this is the only unclamped, sensitive stat)
  double csum = 0, ccnt = 0;
  for (int e = t; e < EDIM - 1; e += 256) {
    double sa = colsum[e], sb = colsum[e + 1];
    double va = (double)colsumsq[e]     - sa * sa / (double)BATCH;
    double vb = (double)colsumsq[e + 1] - sb * sb / (double)BATCH;
    double cov = (double)pairprod[e] - sa * sb / (double)BATCH;
    double corr = cov / sqrt(va * vb);
    if (!isnan(corr)) { csum += corr; ccnt += 1.0; }
  }
  double CS = blk_reduce(csum, sbuf);
  double CN = blk_reduce(ccnt, sbuf);

  double gs = 0, gq = 0;
  for (int e = t; e < EDIM; e += 256) { gs += (double)colsum[e]; gq += (double)colsumsq[e]; }
  double GS = blk_reduce(gs, sbuf);
  double GQ = blk_reduce(gq, sbuf);

  double hent = 0;
  if (t < NBINS) {
    unsigned long long cnt = 0;
    for (int j = 0; j < nreps; ++j) cnt += (unsigned long long)hist[(size_t)j * NBINS + t];
    const double total = (double)BATCH * (double)(EDIM - 1);
    double p = (double)cnt / total;
    if (p > 0.0) hent = -p * log2(p);
  }
  double HE = blk_reduce(hent, sbuf);

  if (t == 0) {
    double entropy = SE / (double)BATCH;
    double spat = SS / (double)BATCH;
    double d_eeg = fmin(entropy * spat * 3.0, 10.0);

    double mag = SM / (double)BATCH;
    double mean_corr = (CN > 0.0) ? (CS / CN) : 0.0;
    double h_fmri = fmin(mag * fabs(mean_corr) * 2.0, 5.0);

    double Nf = (double)BATCH * (double)EDIM;
    double gvar = (GQ - GS * GS / Nf) / (Nf - 1.0);
    double fstd = sqrt(fmax(gvar, 0.0));
    double clz = fmin(HE + 0.3 * fstd, 3.0);

    double fci = (double)wts[0] * (d_eeg / 10.0)
               + (double)wts[1] * (h_fmri / 5.0)
               + (double)wts[2] * (clz / 3.0);
    fci = fmin(fmax(fci, 0.0), 1.0);
    out[0] = (float)fci;
  }
}

extern "C" void kernel_launch(void* const* d_in, const int* in_sizes, int n_in,
                              void* d_out, int out_size, void* d_ws, size_t ws_size,
                              hipStream_t stream) {
  const float* psi = (const float*)d_in[0];
  const float* fld = (const float*)d_in[1];
  const float* wts = (const float*)d_in[2];
  float* out = (float*)d_out;
  float* ws = (float*)d_ws;

  if (ws_size >= (size_t)PRIMARY_WS_BYTES) {
    // ---------------- primary: atomic-free two-stage ----------------
    unsigned* hist_part = (unsigned*)(ws + OFF_HISTP);
    float* cs_part   = ws + OFF_CSP;
    float* cq_part   = ws + OFF_CQP;
    float* pp_part   = ws + OFF_PPP;
    float* rfsq_part = ws + OFF_RFSQP;
    float* row_ent   = ws + OFF_ROWENT;
    float* row_std   = ws + OFF_ROWSTD;
    float* row_fsq   = ws + OFF_ROWFSQ;
    float* colsum    = ws + OFF_COLSUM;
    float* colsumsq  = ws + OFF_COLSQ;
    float* pairprod  = ws + OFF_PAIRP;
    unsigned* hist2  = (unsigned*)(ws + OFF_HIST2);

    // No memset needed: every consumed cell is fully written upstream.
    psi_pass<<<BATCH, 256, 0, stream>>>(psi, hist_part, row_ent, row_std, 0);
    field_pass<<<(NGRP * NCHK) / 4, 256, 0, stream>>>(fld, cs_part, cq_part, pp_part, rfsq_part);
    reduce_pass<<<103, 256, 0, stream>>>(fld, hist_part, cs_part, cq_part, pp_part,
                                         rfsq_part, colsum, colsumsq, pairprod, row_fsq, hist2);
    finalize<<<1, 256, 0, stream>>>(hist2, 8, row_ent, row_std, row_fsq,
                                    colsum, colsumsq, pairprod, wts, out);
  } else {
    // ---------------- fallback: 160 KB ws, global atomics ----------------
    char* wb = (char*)d_ws;
    unsigned* ghist = (unsigned*)(wb);
    float* row_ent  = (float*)(wb + 16384);
    float* row_std  = (float*)(wb + 49152);
    float* row_fsq  = (float*)(wb + 81920);
    float* colsum   = (float*)(wb + 114688);
    float* colsumsq = (float*)(wb + 131072);
    float* pairprod = (float*)(wb + 147456);

    hipMemsetAsync(d_ws, 0, 163840, stream);  // zero atomic targets (0xAA poison)
    psi_pass<<<BATCH, 256, 0, stream>>>(psi, ghist, row_ent, row_std, 1);
    field_pass_fb<<<2048, 256, 0, stream>>>(fld, colsum, colsumsq, pairprod, row_fsq);
    boundary_pass<<<15, 256, 0, stream>>>(fld, pairprod);
    finalize<<<1, 256, 0, stream>>>(ghist, NREP_FB, row_ent, row_std, row_fsq,
                                    colsum, colsumsq, pairprod, wts, out);
  }
}